// Round 3
// baseline (605.297 us; speedup 1.0000x reference)
//
#include <hip/hip_runtime.h>

#define NPIX 4096
#define CIN  256
#define DK   32
#define JSTEP 128
#define NSTEPS (NPIX / JSTEP)

typedef __attribute__((ext_vector_type(8))) short short8;     // 8 bf16 = 4 VGPR (32x32x16 A/B frag)
typedef __attribute__((ext_vector_type(4))) short short4v;    // 4 bf16 = 8B
typedef __attribute__((ext_vector_type(4))) float f32x4;
typedef __attribute__((ext_vector_type(16))) float f32x16;    // 32x32 C/D frag

__device__ __forceinline__ unsigned short f2bf(float f) {
    unsigned int u = __float_as_uint(f);
    unsigned int r = (u + 0x7fffu + ((u >> 16) & 1u)) >> 16;   // RNE
    return (unsigned short)r;
}
__device__ __forceinline__ float bf2f(unsigned short h) {
    return __uint_as_float(((unsigned int)h) << 16);
}

// x[b][c][n] fp32 -> xh[b][n][c] bf16 (hi) and xl[b][n][c] bf16 (residual).
// grid (NPIX/64, CIN/64, B), block 256.
__global__ void prep_kernel(const float* __restrict__ x,
                            unsigned short* __restrict__ xh, unsigned short* __restrict__ xl) {
    __shared__ float xs[64][65];
    const int t = threadIdx.x;
    const int n0 = blockIdx.x * 64, c0 = blockIdx.y * 64, b = blockIdx.z;
#pragma unroll
    for (int k = 0; k < 4; ++k) {
        int id = t + k * 256;
        int c = id >> 4, n4 = (id & 15) * 4;
        float4 v = *reinterpret_cast<const float4*>(&x[(size_t)(b * CIN + c0 + c) * NPIX + n0 + n4]);
        xs[c][n4 + 0] = v.x; xs[c][n4 + 1] = v.y; xs[c][n4 + 2] = v.z; xs[c][n4 + 3] = v.w;
    }
    __syncthreads();
#pragma unroll
    for (int k = 0; k < 4; ++k) {
        int id = t + k * 256;
        int n = id >> 4, c4 = (id & 15) * 4;
        short4v h, l;
#pragma unroll
        for (int j = 0; j < 4; ++j) {
            float v = xs[c4 + j][n];
            unsigned short hb = f2bf(v);
            h[j] = (short)hb;
            l[j] = (short)f2bf(v - bf2f(hb));
        }
        size_t base = (size_t)(b * NPIX + n0 + n) * CIN + c0 + c4;
        *reinterpret_cast<short4v*>(&xh[base]) = h;
        *reinterpret_cast<short4v*>(&xl[base]) = l;
    }
}

// q/k projection via MFMA with bf16 error compensation (3 passes).
// out: qR[b][n][32], kR[b][n][32] bf16. grid (NPIX/64, B), block 128 (2 waves x 32n).
__global__ __launch_bounds__(128) void proj_qk_mfma(
        const unsigned short* __restrict__ xh, const unsigned short* __restrict__ xl,
        const float* __restrict__ wq, const float* __restrict__ bq,
        const float* __restrict__ wk, const float* __restrict__ bk,
        unsigned short* __restrict__ qR, unsigned short* __restrict__ kR) {
    const int t = threadIdx.x, lane = t & 63, w = t >> 6;
    const int li = lane & 31, hi = lane >> 5;
    const int n0 = blockIdx.x * 64 + w * 32, b = blockIdx.y;

    f32x16 accq, acck;
#pragma unroll
    for (int r = 0; r < 16; ++r) { accq[r] = 0.f; acck[r] = 0.f; }

    for (int kk = 0; kk < CIN; kk += 16) {
        size_t xoff = (size_t)(b * NPIX + n0 + li) * CIN + kk + hi * 8;
        short8 ah = *reinterpret_cast<const short8*>(&xh[xoff]);
        short8 al = *reinterpret_cast<const short8*>(&xl[xoff]);
        const float* wqp = &wq[li * CIN + kk + hi * 8];
        const float* wkp = &wk[li * CIN + kk + hi * 8];
        float4 qa = *reinterpret_cast<const float4*>(wqp);
        float4 qb4 = *reinterpret_cast<const float4*>(wqp + 4);
        float4 ka = *reinterpret_cast<const float4*>(wkp);
        float4 kb4 = *reinterpret_cast<const float4*>(wkp + 4);
        float qv[8] = {qa.x, qa.y, qa.z, qa.w, qb4.x, qb4.y, qb4.z, qb4.w};
        float kv[8] = {ka.x, ka.y, ka.z, ka.w, kb4.x, kb4.y, kb4.z, kb4.w};
        short8 wqh, wql, wkh, wkl;
#pragma unroll
        for (int j = 0; j < 8; ++j) {
            unsigned short hq = f2bf(qv[j]);
            wqh[j] = (short)hq; wql[j] = (short)f2bf(qv[j] - bf2f(hq));
            unsigned short hk = f2bf(kv[j]);
            wkh[j] = (short)hk; wkl[j] = (short)f2bf(kv[j] - bf2f(hk));
        }
        accq = __builtin_amdgcn_mfma_f32_32x32x16_bf16(ah, wqh, accq, 0, 0, 0);
        accq = __builtin_amdgcn_mfma_f32_32x32x16_bf16(al, wqh, accq, 0, 0, 0);
        accq = __builtin_amdgcn_mfma_f32_32x32x16_bf16(ah, wql, accq, 0, 0, 0);
        acck = __builtin_amdgcn_mfma_f32_32x32x16_bf16(ah, wkh, acck, 0, 0, 0);
        acck = __builtin_amdgcn_mfma_f32_32x32x16_bf16(al, wkh, acck, 0, 0, 0);
        acck = __builtin_amdgcn_mfma_f32_32x32x16_bf16(ah, wkl, acck, 0, 0, 0);
    }
    const float biasq = bq[li], biask = bk[li];
#pragma unroll
    for (int r = 0; r < 16; ++r) {
        int row = (r & 3) + 8 * (r >> 2) + 4 * hi;
        qR[(size_t)(b * NPIX + n0 + row) * DK + li] = f2bf(accq[r] + biasq);
        kR[(size_t)(b * NPIX + n0 + row) * DK + li] = f2bf(acck[r] + biask);
    }
}

// v projection via MFMA (single pass bf16). out: vR[b][c][n] bf16.
// grid (NPIX/64, CIN/64, B), block 256 (4 waves: 2c x 2n tiles of 32).
__global__ __launch_bounds__(256) void proj_v_mfma(
        const unsigned short* __restrict__ xh, const float* __restrict__ wv,
        const float* __restrict__ bv, unsigned short* __restrict__ vR) {
    const int t = threadIdx.x, lane = t & 63, w = t >> 6;
    const int li = lane & 31, hi = lane >> 5;
    const int n0 = blockIdx.x * 64 + (w >> 1) * 32;
    const int c0 = blockIdx.y * 64 + (w & 1) * 32;
    const int b = blockIdx.z;

    f32x16 acc;
#pragma unroll
    for (int r = 0; r < 16; ++r) acc[r] = 0.f;

    for (int kk = 0; kk < CIN; kk += 16) {
        const float* wp = &wv[(c0 + li) * CIN + kk + hi * 8];
        float4 wa = *reinterpret_cast<const float4*>(wp);
        float4 wb = *reinterpret_cast<const float4*>(wp + 4);
        float wvv[8] = {wa.x, wa.y, wa.z, wa.w, wb.x, wb.y, wb.z, wb.w};
        short8 wh;
#pragma unroll
        for (int j = 0; j < 8; ++j) wh[j] = (short)f2bf(wvv[j]);
        short8 xb = *reinterpret_cast<const short8*>(
            &xh[(size_t)(b * NPIX + n0 + li) * CIN + kk + hi * 8]);
        acc = __builtin_amdgcn_mfma_f32_32x32x16_bf16(wh, xb, acc, 0, 0, 0);
    }
#pragma unroll
    for (int r = 0; r < 16; ++r) {
        int row = (r & 3) + 8 * (r >> 2) + 4 * hi;
        vR[(size_t)(b * CIN + c0 + row) * NPIX + n0 + li] = f2bf(acc[r] + bv[c0 + row]);
    }
}

// Fused attention: E^T via MFMA (j-split across waves), unnormalized exp -> shared
// swizzled Ps, PV via MFMA with V frags from global, row-sum in-kernel, epilogue /l.
// grid (NPIX/64, B), block 512 (8 waves = 2 i-tiles x {4 j-slices for E, 4 c-chunks for PV}).
__global__ __launch_bounds__(512, 2) void attnv_kernel(
        const unsigned short* __restrict__ qR, const unsigned short* __restrict__ kR,
        const unsigned short* __restrict__ vR, const float* __restrict__ xin,
        const float* __restrict__ gamma, float* __restrict__ out) {
    __shared__ unsigned short Ps[2][2][32 * 128];   // [itile][buf][i-row * 128 (16B-group XOR-swizzled)]
    __shared__ float sred[2][4][32];

    const int t = threadIdx.x, lane = t & 63, w = t >> 6;
    const int li = lane & 31, hi = lane >> 5;
    const int it = w >> 2;          // i-tile 0/1
    const int jsl = w & 3;          // E j-slice
    const int cq = w & 3;           // PV c-chunk (64 c)
    const int b = blockIdx.y, i0 = blockIdx.x * 64;
    const int iw = i0 + it * 32;
    const int c0 = cq * 64;

    // persistent Q B-frags (two d-halves of K=16 each)
    const unsigned short* qp = &qR[(size_t)(b * NPIX + iw + li) * DK + hi * 8];
    short8 qb0 = *reinterpret_cast<const short8*>(qp);
    short8 qb1 = *reinterpret_cast<const short8*>(qp + 16);

    float ssum = 0.f;
    short8 kf[2][2];

    auto load_k = [&](int s, short8* dst) {
        const unsigned short* kp =
            &kR[(size_t)(b * NPIX + s * JSTEP + jsl * 32 + li) * DK + hi * 8];
        dst[0] = *reinterpret_cast<const short8*>(kp);
        dst[1] = *reinterpret_cast<const short8*>(kp + 16);
    };
    auto do_E = [&](int s, short8* kfr) {
        f32x16 e;
#pragma unroll
        for (int r = 0; r < 16; ++r) e[r] = 0.f;
        e = __builtin_amdgcn_mfma_f32_32x32x16_bf16(kfr[0], qb0, e, 0, 0, 0);
        e = __builtin_amdgcn_mfma_f32_32x32x16_bf16(kfr[1], qb1, e, 0, 0, 0);
        // e[r]: row j_local = (r&3) + 8*(r>>2) + 4*hi (in 32-j slice), col i = li
        unsigned short* base = &Ps[it][s & 1][li * 128];
#pragma unroll
        for (int g = 0; g < 4; ++g) {
            float p0 = __expf(e[g * 4 + 0]);
            float p1 = __expf(e[g * 4 + 1]);
            float p2 = __expf(e[g * 4 + 2]);
            float p3 = __expf(e[g * 4 + 3]);
            ssum += (p0 + p1) + (p2 + p3);
            short4v pv;
            pv[0] = (short)f2bf(p0); pv[1] = (short)f2bf(p1);
            pv[2] = (short)f2bf(p2); pv[3] = (short)f2bf(p3);
            int jg = jsl * 4 + g;                       // 16B group index (8 bf16)
            *reinterpret_cast<short4v*>(base + (jg ^ (li & 15)) * 8 + hi * 4) = pv;
        }
    };

    f32x16 acc0, acc1;
#pragma unroll
    for (int r = 0; r < 16; ++r) { acc0[r] = 0.f; acc1[r] = 0.f; }

    load_k(0, kf[0]);
    do_E(0, kf[0]);
    load_k(1, kf[1]);
    __syncthreads();

    for (int s = 0; s < NSTEPS; ++s) {
        const int jt = s * JSTEP;
        if (s + 1 < NSTEPS) {
            do_E(s + 1, kf[(s + 1) & 1]);
            if (s + 2 < NSTEPS) load_k(s + 2, kf[s & 1]);
        }
        // PV(s): B-frags from Ps[it][s&1], V A-frags from global
        const unsigned short* pb = &Ps[it][s & 1][li * 128];
        short8 Bf[8];
#pragma unroll
        for (int ks = 0; ks < 8; ++ks) {
            int jg = ks * 2 + hi;
            Bf[ks] = *reinterpret_cast<const short8*>(pb + (jg ^ (li & 15)) * 8);
        }
        {
            const unsigned short* vp =
                &vR[(size_t)(b * CIN + c0 + li) * NPIX + jt + hi * 8];
            short8 Vf[8];
#pragma unroll
            for (int ks = 0; ks < 8; ++ks)
                Vf[ks] = *reinterpret_cast<const short8*>(vp + ks * 16);
#pragma unroll
            for (int ks = 0; ks < 8; ++ks)
                acc0 = __builtin_amdgcn_mfma_f32_32x32x16_bf16(Vf[ks], Bf[ks], acc0, 0, 0, 0);
        }
        {
            const unsigned short* vp =
                &vR[(size_t)(b * CIN + c0 + 32 + li) * NPIX + jt + hi * 8];
            short8 Vf[8];
#pragma unroll
            for (int ks = 0; ks < 8; ++ks)
                Vf[ks] = *reinterpret_cast<const short8*>(vp + ks * 16);
#pragma unroll
            for (int ks = 0; ks < 8; ++ks)
                acc1 = __builtin_amdgcn_mfma_f32_32x32x16_bf16(Vf[ks], Bf[ks], acc1, 0, 0, 0);
        }
        __syncthreads();
    }

    // row sums -> rl (lanes l and l+32 hold same col i)
    ssum += __shfl_xor(ssum, 32);
    if (lane < 32) sred[it][jsl][li] = ssum;
    __syncthreads();
    const float rl = 1.0f / (sred[it][0][li] + sred[it][1][li] + sred[it][2][li] + sred[it][3][li]);
    const float g = gamma[0];
#pragma unroll
    for (int r = 0; r < 16; ++r) {
        int row = (r & 3) + 8 * (r >> 2) + 4 * hi;
        size_t idx0 = (size_t)(b * CIN + c0 + row) * NPIX + iw + li;
        out[idx0] = g * acc0[r] * rl + xin[idx0];
        size_t idx1 = (size_t)(b * CIN + c0 + 32 + row) * NPIX + iw + li;
        out[idx1] = g * acc1[r] * rl + xin[idx1];
    }
}

extern "C" void kernel_launch(void* const* d_in, const int* in_sizes, int n_in,
                              void* d_out, int out_size, void* d_ws, size_t ws_size,
                              hipStream_t stream) {
    const float* x     = (const float*)d_in[0];
    const float* wq    = (const float*)d_in[1];
    const float* bq    = (const float*)d_in[2];
    const float* wk    = (const float*)d_in[3];
    const float* bk    = (const float*)d_in[4];
    const float* wv    = (const float*)d_in[5];
    const float* bv    = (const float*)d_in[6];
    const float* gamma = (const float*)d_in[7];
    float* out = (float*)d_out;

    unsigned short* xh = (unsigned short*)d_ws;               // [B][N][C] bf16, 8 MB
    unsigned short* xl = xh + (size_t)4 * NPIX * CIN;         // 8 MB (reused as vR after proj_qk)
    unsigned short* qR = xl + (size_t)4 * NPIX * CIN;         // [B][N][32] bf16, 1 MB
    unsigned short* kR = qR + (size_t)4 * NPIX * DK;          // 1 MB
    unsigned short* vR = xl;                                  // alias: xl dead after proj_qk

    prep_kernel<<<dim3(64, 4, 4), 256, 0, stream>>>(x, xh, xl);
    proj_qk_mfma<<<dim3(64, 4), 128, 0, stream>>>(xh, xl, wq, bq, wk, bk, qR, kR);
    proj_v_mfma<<<dim3(64, 4, 4), 256, 0, stream>>>(xh, wv, bv, vR);
    attnv_kernel<<<dim3(64, 4), 512, 0, stream>>>(qR, kR, vR, x, gamma, out);
}

// Round 4
// 157.310 us; speedup vs baseline: 3.8478x; 3.8478x over previous
//
#include <hip/hip_runtime.h>

#define NPIX 4096
#define CIN  256
#define DK   32

typedef __attribute__((ext_vector_type(8))) short short8;     // 8 bf16 = one MFMA A/B frag reg group
typedef __attribute__((ext_vector_type(4))) short short4v;    // 8B
typedef __attribute__((ext_vector_type(16))) float f32x16;    // 32x32 C/D frag

__device__ __forceinline__ unsigned short f2bf(float f) {
    unsigned int u = __float_as_uint(f);
    return (unsigned short)((u + 0x7fffu + ((u >> 16) & 1u)) >> 16);   // RNE
}
__device__ __forceinline__ float bf2f(unsigned short h) {
    return __uint_as_float(((unsigned int)h) << 16);
}

// ---------------------------------------------------------------------------
// Weight prep: wq/wk (hi+residual) and wv (hi) into B/A-frag tile order.
// frag = 64 lanes x 16B, lane li = row (d or c), elems = k-span (c of x).
// grid (16 kchunks, 12), 64 threads.
__global__ void wprep_kernel(const float* __restrict__ wq, const float* __restrict__ wk,
                             const float* __restrict__ wv,
                             unsigned short* __restrict__ wqh, unsigned short* __restrict__ wql,
                             unsigned short* __restrict__ wkh, unsigned short* __restrict__ wkl,
                             unsigned short* __restrict__ wvh) {
    const int lane = threadIdx.x & 63, li = lane & 31, hi = lane >> 5;
    const int kc = blockIdx.x, y = blockIdx.y;
    if (y < 4) {
        const float* m = (y < 2) ? wq : wk;
        short8 h8, l8;
#pragma unroll
        for (int e = 0; e < 8; ++e) {
            float v = m[li * CIN + kc * 16 + hi * 8 + e];
            unsigned short hb = f2bf(v);
            h8[e] = (short)hb;
            l8[e] = (short)f2bf(v - bf2f(hb));
        }
        unsigned short* dst = (y == 0) ? wqh : (y == 1) ? wql : (y == 2) ? wkh : wkl;
        *reinterpret_cast<short8*>(&dst[kc * 512 + lane * 8]) = (y & 1) ? l8 : h8;
    } else {
        const int cblk = y - 4;
        short8 h8;
#pragma unroll
        for (int e = 0; e < 8; ++e)
            h8[e] = (short)f2bf(wv[(cblk * 32 + li) * CIN + kc * 16 + hi * 8 + e]);
        *reinterpret_cast<short8*>(&wvh[(cblk * 16 + kc) * 512 + lane * 8]) = h8;
    }
}

// ---------------------------------------------------------------------------
// x[b][c][n] fp32 -> xh/xl frag tiles: frag(b, nblk, kc): lane li = n-local,
// elems = c-span (A-frag for proj MFMAs). grid (32, 4, 4), block 256.
__global__ __launch_bounds__(256) void prep_kernel(const float* __restrict__ x,
                                                   unsigned short* __restrict__ xh,
                                                   unsigned short* __restrict__ xl) {
    __shared__ float xs[64][132];    // 64c x 128n fp32, pad 132 (16B-aligned rows)
    const int t = threadIdx.x;
    const int n0 = blockIdx.x * 128, c0 = blockIdx.y * 64, b = blockIdx.z;
#pragma unroll
    for (int k = 0; k < 8; ++k) {
        int id = t + k * 256;
        int row = id >> 5, col4 = (id & 31) * 4;
        float4 v = *reinterpret_cast<const float4*>(&x[(size_t)(b * CIN + c0 + row) * NPIX + n0 + col4]);
        xs[row][col4 + 0] = v.x; xs[row][col4 + 1] = v.y;
        xs[row][col4 + 2] = v.z; xs[row][col4 + 3] = v.w;
    }
    __syncthreads();
    const int lane = t & 63, li = lane & 31, hi = lane >> 5, w = t >> 6;
#pragma unroll
    for (int kcl = 0; kcl < 4; ++kcl) {
        short8 h8, l8;
#pragma unroll
        for (int e = 0; e < 8; ++e) {
            float v = xs[kcl * 16 + hi * 8 + e][w * 32 + li];
            unsigned short hb = f2bf(v);
            h8[e] = (short)hb;
            l8[e] = (short)f2bf(v - bf2f(hb));
        }
        size_t f = ((size_t)(b * 128 + blockIdx.x * 4 + w) * 16 + blockIdx.y * 4 + kcl) * 512 + lane * 8;
        *reinterpret_cast<short8*>(&xh[f]) = h8;
        *reinterpret_cast<short8*>(&xl[f]) = l8;
    }
}

// ---------------------------------------------------------------------------
// Q/K projection (bf16 error-compensated, 3 MFMA each). Outputs tiled frags:
// qfrag/kfrag(b, nblk, dhalf): lane li = n (i or j), elems = d-span.
// grid (64, 4), block 128 (2 waves, one 32n tile each).
__global__ __launch_bounds__(128) void proj_qk_kernel(
        const unsigned short* __restrict__ xh, const unsigned short* __restrict__ xl,
        const unsigned short* __restrict__ wqh, const unsigned short* __restrict__ wql,
        const unsigned short* __restrict__ wkh, const unsigned short* __restrict__ wkl,
        const float* __restrict__ bq, const float* __restrict__ bk,
        unsigned short* __restrict__ qfrag, unsigned short* __restrict__ kfrag) {
    __shared__ unsigned short ts[2][32][40];
    const int t = threadIdx.x, lane = t & 63, li = lane & 31, hi = lane >> 5, w = t >> 6;
    const int nblk = blockIdx.x * 2 + w, b = blockIdx.y;
    f32x16 accq, acck;
#pragma unroll
    for (int r = 0; r < 16; ++r) { accq[r] = 0.f; acck[r] = 0.f; }
    for (int kc = 0; kc < 16; ++kc) {
        size_t xf = ((size_t)(b * 128 + nblk) * 16 + kc) * 512 + lane * 8;
        short8 ah = *reinterpret_cast<const short8*>(&xh[xf]);
        short8 al = *reinterpret_cast<const short8*>(&xl[xf]);
        const int wf = kc * 512 + lane * 8;
        short8 qh = *reinterpret_cast<const short8*>(&wqh[wf]);
        short8 ql = *reinterpret_cast<const short8*>(&wql[wf]);
        short8 kh = *reinterpret_cast<const short8*>(&wkh[wf]);
        short8 kl = *reinterpret_cast<const short8*>(&wkl[wf]);
        accq = __builtin_amdgcn_mfma_f32_32x32x16_bf16(ah, qh, accq, 0, 0, 0);
        accq = __builtin_amdgcn_mfma_f32_32x32x16_bf16(al, qh, accq, 0, 0, 0);
        accq = __builtin_amdgcn_mfma_f32_32x32x16_bf16(ah, ql, accq, 0, 0, 0);
        acck = __builtin_amdgcn_mfma_f32_32x32x16_bf16(ah, kh, acck, 0, 0, 0);
        acck = __builtin_amdgcn_mfma_f32_32x32x16_bf16(al, kh, acck, 0, 0, 0);
        acck = __builtin_amdgcn_mfma_f32_32x32x16_bf16(ah, kl, acck, 0, 0, 0);
    }
    const float biasq = bq[li], biask = bk[li];
    // transpose q tile (row=n, col=d) -> frag (lane=n, elems=d)
#pragma unroll
    for (int r = 0; r < 16; ++r) {
        int row = (r & 3) + 8 * (r >> 2) + 4 * hi;
        ts[w][row][li] = f2bf(accq[r] + biasq);
    }
    {
        short8 f0 = *reinterpret_cast<const short8*>(&ts[w][li][hi * 8]);
        short8 f1 = *reinterpret_cast<const short8*>(&ts[w][li][16 + hi * 8]);
        size_t qo = ((size_t)(b * 128 + nblk) * 2) * 512 + lane * 8;
        *reinterpret_cast<short8*>(&qfrag[qo]) = f0;
        *reinterpret_cast<short8*>(&qfrag[qo + 512]) = f1;
    }
#pragma unroll
    for (int r = 0; r < 16; ++r) {
        int row = (r & 3) + 8 * (r >> 2) + 4 * hi;
        ts[w][row][li] = f2bf(acck[r] + biask);
    }
    {
        short8 f0 = *reinterpret_cast<const short8*>(&ts[w][li][hi * 8]);
        short8 f1 = *reinterpret_cast<const short8*>(&ts[w][li][16 + hi * 8]);
        size_t ko = ((size_t)(b * 128 + nblk) * 2) * 512 + lane * 8;
        *reinterpret_cast<short8*>(&kfrag[ko]) = f0;
        *reinterpret_cast<short8*>(&kfrag[ko + 512]) = f1;
    }
}

// ---------------------------------------------------------------------------
// V projection -> vfrag(b, cblk, jchunk): lane li = c-local, elems = j-span
// (A-frag for PV). grid (32, 8, 4), block 256 (4 waves, one 32n tile each).
__global__ __launch_bounds__(256) void proj_v_kernel(
        const unsigned short* __restrict__ xh, const unsigned short* __restrict__ wvh,
        const float* __restrict__ bv, unsigned short* __restrict__ vfrag) {
    __shared__ unsigned short ts[4][32][40];
    const int t = threadIdx.x, lane = t & 63, li = lane & 31, hi = lane >> 5, w = t >> 6;
    const int nblk = blockIdx.x * 4 + w, cblk = blockIdx.y, b = blockIdx.z;
    f32x16 acc;
#pragma unroll
    for (int r = 0; r < 16; ++r) acc[r] = 0.f;
    for (int kc = 0; kc < 16; ++kc) {
        short8 a = *reinterpret_cast<const short8*>(&wvh[(cblk * 16 + kc) * 512 + lane * 8]);
        short8 xb = *reinterpret_cast<const short8*>(
            &xh[((size_t)(b * 128 + nblk) * 16 + kc) * 512 + lane * 8]);
        acc = __builtin_amdgcn_mfma_f32_32x32x16_bf16(a, xb, acc, 0, 0, 0);
    }
    // D: row = c-local, col = n. Transpose -> frag lane = c, elems = j(n).
#pragma unroll
    for (int r = 0; r < 16; ++r) {
        int row = (r & 3) + 8 * (r >> 2) + 4 * hi;
        ts[w][row][li] = f2bf(acc[r] + bv[cblk * 32 + row]);
    }
#pragma unroll
    for (int jcl = 0; jcl < 2; ++jcl) {
        short8 f = *reinterpret_cast<const short8*>(&ts[w][li][jcl * 16 + hi * 8]);
        size_t off = ((size_t)(b * 8 + cblk) * 256 + nblk * 2 + jcl) * 512 + lane * 8;
        *reinterpret_cast<short8*>(&vfrag[off]) = f;
    }
}

// ---------------------------------------------------------------------------
// Fused attention. 16 waves: 8 E-waves produce exp(QK^T) for step s+1 into
// double-buffered swizzled Ps; 8 PV-waves (32c each) accumulate both i-tiles.
// j-step 128, 32 steps, one barrier per step. All global loads = 1KB coalesced.
__global__ __launch_bounds__(1024) void attnv_kernel(
        const unsigned short* __restrict__ qfrag, const unsigned short* __restrict__ kfrag,
        const unsigned short* __restrict__ vfrag, const float* __restrict__ xin,
        const float* __restrict__ gamma, float* __restrict__ out) {
    __shared__ unsigned short Ps[4][32 * 128];   // [it*2+buf][i*128 + swizzled j-groups]
    __shared__ float sred[2][4][32];
    const int t = threadIdx.x, lane = t & 63, li = lane & 31, hi = lane >> 5, w = t >> 6;
    // XCD-aware swizzle: each XCD pair serves one batch -> V stays in its L2
    const int blk = blockIdx.x;
    const int xcd = blk & 7, slot = blk >> 3;
    const int b = xcd >> 1;
    const int ipos = (xcd & 1) * 32 + slot;      // 64-i tile in [0,64)
    const bool isE = (w < 8);
    const int itE = (w >> 2) & 1, sl = w & 3;    // E: i-tile, 32j-slice
    const int cq = w & 7;                        // PV: 32c chunk

    short8 qb0, qb1;
    float ssum = 0.f;
    if (isE) {
        size_t qoff = ((size_t)(b * 128 + ipos * 2 + itE) * 2) * 512 + lane * 8;
        qb0 = *reinterpret_cast<const short8*>(&qfrag[qoff]);
        qb1 = *reinterpret_cast<const short8*>(&qfrag[qoff + 512]);
    }

    f32x16 acc0, acc1;
#pragma unroll
    for (int r = 0; r < 16; ++r) { acc0[r] = 0.f; acc1[r] = 0.f; }

    auto do_E = [&](int s) {
        const int buf = s & 1;
        const int jblk = s * 4 + sl;             // 32j block in [0,128)
        size_t koff = ((size_t)(b * 128 + jblk) * 2) * 512 + lane * 8;
        short8 k0 = *reinterpret_cast<const short8*>(&kfrag[koff]);
        short8 k1 = *reinterpret_cast<const short8*>(&kfrag[koff + 512]);
        f32x16 e;
#pragma unroll
        for (int r = 0; r < 16; ++r) e[r] = 0.f;
        e = __builtin_amdgcn_mfma_f32_32x32x16_bf16(k0, qb0, e, 0, 0, 0);
        e = __builtin_amdgcn_mfma_f32_32x32x16_bf16(k1, qb1, e, 0, 0, 0);
        unsigned short* base = &Ps[itE * 2 + buf][li * 128];
#pragma unroll
        for (int g = 0; g < 4; ++g) {
            float p0 = __expf(e[g * 4 + 0]);
            float p1 = __expf(e[g * 4 + 1]);
            float p2 = __expf(e[g * 4 + 2]);
            float p3 = __expf(e[g * 4 + 3]);
            ssum += (p0 + p1) + (p2 + p3);
            short4v pv;
            pv[0] = (short)f2bf(p0); pv[1] = (short)f2bf(p1);
            pv[2] = (short)f2bf(p2); pv[3] = (short)f2bf(p3);
            int jg = sl * 4 + g;
            *reinterpret_cast<short4v*>(&base[((jg ^ li) & 15) * 8 + hi * 4]) = pv;
        }
    };
    auto do_PV = [&](int s) {
        const int buf = s & 1;
        short8 Af[8];
        size_t vbase = ((size_t)(b * 8 + cq) * 256 + s * 8) * 512 + lane * 8;
#pragma unroll
        for (int kc = 0; kc < 8; ++kc)
            Af[kc] = *reinterpret_cast<const short8*>(&vfrag[vbase + kc * 512]);
#pragma unroll
        for (int kc = 0; kc < 8; ++kc) {
            int jg = kc * 2 + hi;
            int pos = (jg ^ li) & 15;
            short8 B0 = *reinterpret_cast<const short8*>(&Ps[buf][li * 128 + pos * 8]);
            short8 B1 = *reinterpret_cast<const short8*>(&Ps[2 + buf][li * 128 + pos * 8]);
            acc0 = __builtin_amdgcn_mfma_f32_32x32x16_bf16(Af[kc], B0, acc0, 0, 0, 0);
            acc1 = __builtin_amdgcn_mfma_f32_32x32x16_bf16(Af[kc], B1, acc1, 0, 0, 0);
        }
    };

    if (isE) do_E(0);
    __syncthreads();
    for (int s = 0; s < NPIX / 128; ++s) {
        if (isE) {
            if (s + 1 < NPIX / 128) do_E(s + 1);
        } else {
            do_PV(s);
        }
        __syncthreads();
    }
    if (isE) {
        ssum += __shfl_xor(ssum, 32);
        if (lane < 32) sred[itE][sl][li] = ssum;
    }
    __syncthreads();
    if (!isE) {
        const float rl0 = 1.0f / (sred[0][0][li] + sred[0][1][li] + sred[0][2][li] + sred[0][3][li]);
        const float rl1 = 1.0f / (sred[1][0][li] + sred[1][1][li] + sred[1][2][li] + sred[1][3][li]);
        const float g = gamma[0];
#pragma unroll
        for (int r = 0; r < 16; ++r) {
            int c = cq * 32 + (r & 3) + 8 * (r >> 2) + 4 * hi;
            size_t rowb = (size_t)(b * CIN + c) * NPIX + ipos * 64;
            out[rowb + li]      = g * acc0[r] * rl0 + xin[rowb + li];
            out[rowb + 32 + li] = g * acc1[r] * rl1 + xin[rowb + 32 + li];
        }
    }
}

extern "C" void kernel_launch(void* const* d_in, const int* in_sizes, int n_in,
                              void* d_out, int out_size, void* d_ws, size_t ws_size,
                              hipStream_t stream) {
    const float* x     = (const float*)d_in[0];
    const float* wq    = (const float*)d_in[1];
    const float* bq    = (const float*)d_in[2];
    const float* wk    = (const float*)d_in[3];
    const float* bk    = (const float*)d_in[4];
    const float* wv    = (const float*)d_in[5];
    const float* bv    = (const float*)d_in[6];
    const float* gamma = (const float*)d_in[7];
    float* out = (float*)d_out;

    unsigned short* xh = (unsigned short*)d_ws;               // 8 MB
    unsigned short* xl = xh + (size_t)4 * 128 * 16 * 512;     // 8 MB (dead after proj_qk)
    unsigned short* qf = xl + (size_t)4 * 128 * 16 * 512;     // 1 MB
    unsigned short* kf = qf + (size_t)4 * 128 * 2 * 512;      // 1 MB
    unsigned short* wqh = kf + (size_t)4 * 128 * 2 * 512;
    unsigned short* wql = wqh + 16 * 512;
    unsigned short* wkh = wql + 16 * 512;
    unsigned short* wkl = wkh + 16 * 512;
    unsigned short* wvh = wkl + 16 * 512;                     // 8*16 frags
    unsigned short* vf = xl;                                  // alias: reuse xl

    wprep_kernel<<<dim3(16, 12), 64, 0, stream>>>(wq, wk, wv, wqh, wql, wkh, wkl, wvh);
    prep_kernel<<<dim3(32, 4, 4), 256, 0, stream>>>(x, xh, xl);
    proj_qk_kernel<<<dim3(64, 4), 128, 0, stream>>>(xh, xl, wqh, wql, wkh, wkl, bq, bk, qf, kf);
    proj_v_kernel<<<dim3(32, 8, 4), 256, 0, stream>>>(xh, wvh, bv, vf);
    attnv_kernel<<<dim3(256), 1024, 0, stream>>>(qf, kf, vf, x, gamma, out);
}